// Round 12
// baseline (157.532 us; speedup 1.0000x reference)
//
#include <hip/hip_runtime.h>

// PositionAttentionModule: B=2,C=64,C8=8,H=W=96,N=9216
// Round 12: R11 numerics + double-buffered v_s (one barrier per chunk,
// V-load latency hidden behind a full chunk of compute). MCHUNK=128,
// PSTR=132 (conflict structure HW-validated in R9), LDS 33.8 KB.

#define BN 2
#define CC 64
#define C8K 8
#define NN 9216
#define MCHUNK 128
#define TQ 128                // query rows per block (4 waves x 32)
#define NBLKQ (NN / TQ)       // 72
#define PREP_PX 64
#define LOG2E 1.44269504f
#define PSTR 132              // shorts; 264B row: dword-pair stride 33 (odd mod 16)

typedef __attribute__((ext_vector_type(8))) short short8;
typedef __attribute__((ext_vector_type(16))) float f32x16;

// float offsets into workspace
#define OFF_QB 0                                   // bf16 [b][n][8], prescaled by log2e
#define OFF_KT (OFF_QB + BN * NN * C8K / 2)        // bf16 [b][m][8]
#define OFF_VT (OFF_KT + BN * NN * C8K / 2)        // bf16 [b][c][m]
#define OFF_PACC (OFF_VT + BN * NN * CC / 2)       // bf16 [sp][b][c][n]
// PSUM (fp32 [sp][b][n]) follows PACC

static __device__ inline unsigned f2bf(float x) {
    unsigned u = __builtin_bit_cast(unsigned, x);
    return (u + 0x7fff + ((u >> 16) & 1)) >> 16;   // RNE
}

#if __has_builtin(__builtin_amdgcn_cvt_pk_bf16_f32)
typedef __attribute__((ext_vector_type(2))) __bf16 bf16x2;
static __device__ inline unsigned pk_pair(float lo, float hi) {
    bf16x2 v = __builtin_amdgcn_cvt_pk_bf16_f32(lo, hi);   // lo -> D.lo, hi -> D.hi
    return __builtin_bit_cast(unsigned, v);
}
#else
static __device__ inline unsigned pk_pair(float lo, float hi) {
    unsigned ulo = __builtin_bit_cast(unsigned, lo) + 0x8000u;
    unsigned uhi = __builtin_bit_cast(unsigned, hi) + 0x8000u;
    return __builtin_amdgcn_perm(uhi, ulo, 0x07060302u);
}
#endif

__global__ __launch_bounds__(256) void pam_prep(
    const float* __restrict__ fm, const float* __restrict__ depth,
    const float* __restrict__ wa, const float* __restrict__ ba,
    const float* __restrict__ wb, const float* __restrict__ bb,
    const float* __restrict__ wc, const float* __restrict__ bc,
    const float* __restrict__ wd, const float* __restrict__ bd,
    unsigned short* __restrict__ Qb, unsigned short* __restrict__ Kt,
    unsigned short* __restrict__ Vt)
{
    __shared__ float s_wd[CC * CC];
    __shared__ float s_wb[C8K * CC], s_wc[C8K * CC];
    __shared__ float s_wa[CC], s_ba[CC], s_bd[CC];
    __shared__ float s_bb[C8K], s_bc[C8K];
    __shared__ float qp[4][PREP_PX][C8K + 1];

    int t = threadIdx.x;
    for (int i = t; i < CC * CC; i += 256) s_wd[i] = wd[i];
    for (int i = t; i < C8K * CC; i += 256) { s_wb[i] = wb[i]; s_wc[i] = wc[i]; }
    if (t < CC) { s_wa[t] = wa[t]; s_ba[t] = ba[t]; s_bd[t] = bd[t]; }
    if (t < C8K) { s_bb[t] = bb[t]; s_bc[t] = bc[t]; }
    __syncthreads();

    int px0 = blockIdx.x * PREP_PX;
    int b = px0 / NN;
    int m0 = px0 - b * NN;
    int px = t & 63, w = t >> 6;
    int m = m0 + px;
    int gidx = px0 + px;

    float d = depth[gidx];
    float df[CC];
#pragma unroll
    for (int i = 0; i < CC; ++i) df[i] = fmaxf(s_wa[i] * d + s_ba[i], 0.0f);

#pragma unroll 4
    for (int cc = 0; cc < 16; ++cc) {
        int c = w * 16 + cc;
        float acc = s_bd[c];
#pragma unroll
        for (int i = 0; i < CC; i += 4) {
            float4 wv = *(const float4*)&s_wd[c * CC + i];
            acc += wv.x * df[i] + wv.y * df[i + 1] + wv.z * df[i + 2] + wv.w * df[i + 3];
        }
        Vt[(b * CC + c) * NN + m] = (unsigned short)f2bf(acc);
    }

    {
        float k0 = s_bc[2 * w], k1 = s_bc[2 * w + 1];
#pragma unroll
        for (int i = 0; i < CC; ++i) {
            k0 += s_wc[(2 * w) * CC + i] * df[i];
            k1 += s_wc[(2 * w + 1) * CC + i] * df[i];
        }
        unsigned pkv = f2bf(k0) | (f2bf(k1) << 16);
        *(unsigned*)&Kt[(b * NN + m) * C8K + 2 * w] = pkv;
    }

    {
        float q[C8K];
#pragma unroll
        for (int k = 0; k < C8K; ++k) q[k] = (w == 0) ? s_bb[k] : 0.0f;
#pragma unroll
        for (int ii = 0; ii < 16; ++ii) {
            int i = w * 16 + ii;
            float f = fm[(b * CC + i) * NN + m];
#pragma unroll
            for (int k = 0; k < C8K; ++k) q[k] += s_wb[k * CC + i] * f;
        }
#pragma unroll
        for (int k = 0; k < C8K; ++k) qp[w][px][k] = q[k];
    }
    __syncthreads();
    {
        int px2 = t >> 2, k2 = (t & 3) * 2;
        float a0 = (qp[0][px2][k2] + qp[1][px2][k2] + qp[2][px2][k2] + qp[3][px2][k2]) * LOG2E;
        float a1 = (qp[0][px2][k2 + 1] + qp[1][px2][k2 + 1] + qp[2][px2][k2 + 1] + qp[3][px2][k2 + 1]) * LOG2E;
        unsigned pkv = f2bf(a0) | (f2bf(a1) << 16);
        *(unsigned*)&Qb[(px0 + px2) * C8K + k2] = pkv;
    }
}

// grid (72, S, B), block 256 = 4 waves; wave w -> qrows [w*32, w*32+32).
__global__ __launch_bounds__(256, 4) void pam_attn(
    const unsigned short* __restrict__ Qb, const unsigned short* __restrict__ Kt,
    const unsigned short* __restrict__ Vt,
    unsigned short* __restrict__ PACC, float* __restrict__ PSUM,
    int m_range)
{
    __shared__ unsigned short v_s[2][CC * PSTR];   // 33.8 KB bf16 [buf][c][m]

    int t = threadIdx.x;
    int n0 = blockIdx.x * TQ;
    int split = blockIdx.y;
    int b = blockIdx.z;
    int m_start = split * m_range;
    int nchunk = m_range / MCHUNK;

    int lane = t & 63, w = t >> 6;
    int l31 = lane & 31, half = lane >> 5;

    // QK B-frag: Q[qrow=l31][k] for k<8 (half0); half1 k=8 slot carries the
    // folded shift constant -12*log2e; k=9..15 are zero.
    short8 bq = {};
    if (lane < 32) bq = *(const short8*)&Qb[(b * NN + n0 + w * 32 + l31) * C8K];
    else           bq[0] = (short)f2bf(-12.0f * LOG2E);

    // per-lane masks: force A-frag element 0 to 1.0 on half1 lanes (k=8 slot)
    const unsigned mand = half ? 0xFFFF0000u : 0xFFFFFFFFu;
    const unsigned mor  = half ? 0x00003F80u : 0u;

    f32x16 acc0 = {}, acc1 = {};
    float2 rs2 = {0.0f, 0.0f};

    int vrow = t >> 2, vsl = t & 3;   // staging: channel row, 16B-segment lane
    const int vfoff = l31 * PSTR + half * 4;   // A-frag base offset (permuted k)

    // ---- prologue: stage chunk 0 into buffer 0 ----
    {
        const unsigned short* gsrc = &Vt[(b * CC + vrow) * NN + m_start + vsl * 8];
        ulonglong2 vb[4];
#pragma unroll
        for (int i = 0; i < 4; ++i) vb[i] = *(const ulonglong2*)(gsrc + i * 32);
        unsigned long long* ldst = (unsigned long long*)&v_s[0][vrow * PSTR + vsl * 8];
#pragma unroll
        for (int i = 0; i < 4; ++i) {
            ldst[i * 8 + 0] = vb[i].x;
            ldst[i * 8 + 1] = vb[i].y;
        }
    }
    __syncthreads();

    for (int ch = 0; ch < nchunk; ++ch) {
        int m0 = m_start + ch * MCHUNK;
        int nxt = ch + 1;

        // ---- K-frags for current chunk (issued first; compute's first MFMA
        // waits on these with vmcnt(N) keeping the V-prefetch in flight) ----
        union { unsigned u[4]; short8 s8; } aK[4];
#pragma unroll
        for (int mt = 0; mt < 4; ++mt)
            aK[mt].s8 = *(const short8*)&Kt[(b * NN + m0 + mt * 32 + l31) * C8K];

        // ---- V prefetch for chunk+1 (no LDS dependency; latency hidden
        // behind this chunk's compute) ----
        ulonglong2 vbuf[4];
        if (nxt < nchunk) {
            const unsigned short* gsrc =
                &Vt[(b * CC + vrow) * NN + m0 + MCHUNK + vsl * 8];
#pragma unroll
            for (int i = 0; i < 4; ++i)
                vbuf[i] = *(const ulonglong2*)(gsrc + i * 32);
        }

#pragma unroll
        for (int mt = 0; mt < 4; ++mt)
            aK[mt].u[0] = (aK[mt].u[0] & mand) | mor;

        const unsigned short* bufc = v_s[ch & 1];
        const unsigned short* vr0 = bufc + vfoff;
        const unsigned short* vr1 = bufc + 32 * PSTR + vfoff;

#pragma unroll
        for (int mt = 0; mt < 4; ++mt) {
            // ---- QK^T transposed: D[m][qrow], already shifted & log2-scaled ----
            f32x16 s = __builtin_amdgcn_mfma_f32_32x32x16_bf16(aK[mt].s8, bq, (f32x16){}, 0, 0, 0);
            // ---- raw v_exp_f32 + rowsum + pack ----
            unsigned qd[8];
#pragma unroll
            for (int i = 0; i < 8; ++i) {
                float e0 = __builtin_amdgcn_exp2f(s[2 * i]);
                float e1 = __builtin_amdgcn_exp2f(s[2 * i + 1]);
                rs2.x += e0; rs2.y += e1;
                qd[i] = pk_pair(e0, e1);
            }
            // ---- PV: B = qd verbatim; A = v_s with permuted k-order ----
#pragma unroll
            for (int ks = 0; ks < 2; ++ks) {
                union { unsigned u[4]; short8 s8; } Bp;
#pragma unroll
                for (int i = 0; i < 4; ++i) Bp.u[i] = qd[ks * 4 + i];
                const int off = mt * 32 + ks * 16;
                union { unsigned long long d[2]; short8 s8; } A0, A1;
                A0.d[0] = *(const unsigned long long*)(vr0 + off);
                A0.d[1] = *(const unsigned long long*)(vr0 + off + 8);
                A1.d[0] = *(const unsigned long long*)(vr1 + off);
                A1.d[1] = *(const unsigned long long*)(vr1 + off + 8);
                acc0 = __builtin_amdgcn_mfma_f32_32x32x16_bf16(A0.s8, Bp.s8, acc0, 0, 0, 0);
                acc1 = __builtin_amdgcn_mfma_f32_32x32x16_bf16(A1.s8, Bp.s8, acc1, 0, 0, 0);
            }
        }

        // ---- write prefetched chunk into the other buffer; one barrier.
        // Legal: buf[nxt&1] was last read in chunk ch-1, and every wave
        // passed the iter-(ch-1) barrier after those reads. ----
        if (nxt < nchunk) {
            unsigned long long* ldst =
                (unsigned long long*)&v_s[nxt & 1][vrow * PSTR + vsl * 8];
#pragma unroll
            for (int i = 0; i < 4; ++i) {
                ldst[i * 8 + 0] = vbuf[i].x;
                ldst[i * 8 + 1] = vbuf[i].y;
            }
            __syncthreads();
        }
    }

    // ---- epilogue ----
    float rsum = rs2.x + rs2.y;
    rsum += __shfl_xor(rsum, 32);
    if (lane < 32)
        PSUM[(split * BN + b) * NN + n0 + w * 32 + l31] = rsum;

    // D[c][qrow]: lane l31 = qrow (n), reg -> c = 8*(reg>>2)+(reg&3)+4*half
    {
        int slabc = (split * BN + b) * CC;
        int nidx = n0 + w * 32 + l31;
#pragma unroll
        for (int reg = 0; reg < 16; ++reg) {
            int c = 8 * (reg >> 2) + (reg & 3) + 4 * half;
            PACC[(slabc + c) * NN + nidx] = (unsigned short)f2bf(acc0[reg]);
            PACC[(slabc + 32 + c) * NN + nidx] = (unsigned short)f2bf(acc1[reg]);
        }
    }
}

// out[b][c][n] = sum_sp PACC[sp][b][c][n] / sum_sp PSUM[sp][b][n]
__global__ __launch_bounds__(256) void pam_norm(
    const unsigned short* __restrict__ PACC, const float* __restrict__ PSUM,
    float* __restrict__ out, int S)
{
    __shared__ float s_inv[64];
    int t = threadIdx.x;
    int n0 = blockIdx.x * 64;
    int b = blockIdx.y;
    if (t < 64) {
        float s = 0.0f;
        for (int sp = 0; sp < S; ++sp) s += PSUM[(sp * BN + b) * NN + n0 + t];
        s_inv[t] = 1.0f / s;
    }
    __syncthreads();

    int c = t >> 2, ng = t & 3;       // channel, 16-n group
    int nb = n0 + ng * 16;
    float a[16];
#pragma unroll
    for (int j = 0; j < 16; ++j) a[j] = 0.0f;

    for (int sp = 0; sp < S; ++sp) {
        const unsigned short* p = &PACC[((sp * BN + b) * CC + c) * NN + nb];
        uint4 u0 = *(const uint4*)p;
        uint4 u1 = *(const uint4*)(p + 8);
        const unsigned uu[8] = {u0.x, u0.y, u0.z, u0.w, u1.x, u1.y, u1.z, u1.w};
#pragma unroll
        for (int i = 0; i < 8; ++i) {
            a[2 * i]     += __builtin_bit_cast(float, uu[i] << 16);
            a[2 * i + 1] += __builtin_bit_cast(float, uu[i] & 0xffff0000u);
        }
    }
    float* o = &out[(b * CC + c) * NN + nb];
#pragma unroll
    for (int j4 = 0; j4 < 4; ++j4) {
        float4 v;
        v.x = a[j4 * 4 + 0] * s_inv[ng * 16 + j4 * 4 + 0];
        v.y = a[j4 * 4 + 1] * s_inv[ng * 16 + j4 * 4 + 1];
        v.z = a[j4 * 4 + 2] * s_inv[ng * 16 + j4 * 4 + 2];
        v.w = a[j4 * 4 + 3] * s_inv[ng * 16 + j4 * 4 + 3];
        *(float4*)(o + j4 * 4) = v;
    }
}

extern "C" void kernel_launch(void* const* d_in, const int* in_sizes, int n_in,
                              void* d_out, int out_size, void* d_ws, size_t ws_size,
                              hipStream_t stream) {
    const float* fm    = (const float*)d_in[0];
    const float* depth = (const float*)d_in[1];
    const float* wa    = (const float*)d_in[2];
    const float* ba    = (const float*)d_in[3];
    const float* wb    = (const float*)d_in[4];
    const float* bb    = (const float*)d_in[5];
    const float* wc    = (const float*)d_in[6];
    const float* bc    = (const float*)d_in[7];
    const float* wd    = (const float*)d_in[8];
    const float* bd    = (const float*)d_in[9];
    float* out = (float*)d_out;

    float* ws = (float*)d_ws;
    unsigned short* Qb = (unsigned short*)(ws + OFF_QB);
    unsigned short* Kt = (unsigned short*)(ws + OFF_KT);
    unsigned short* Vt = (unsigned short*)(ws + OFF_VT);
    unsigned short* PACC = (unsigned short*)(ws + OFF_PACC);

    // pick largest split whose PACC(bf16)+PSUM fit: 12 -> 8 -> 4
    int S = 12;
    while (S > 4) {
        size_t need = (size_t)OFF_PACC * 4
                    + (size_t)S * BN * NN * CC * 2      // PACC bf16
                    + (size_t)S * BN * NN * 4;          // PSUM fp32
        if (need <= ws_size) break;
        S -= 4;
    }
    float* PSUM = (float*)(PACC + (size_t)S * BN * NN * CC);
    int m_range = NN / S;   // 12->768, 8->1152, 4->2304; all % 128 == 0

    pam_prep<<<dim3((BN * NN) / PREP_PX), 256, 0, stream>>>(
        fm, depth, wa, ba, wb, bb, wc, bc, wd, bd, Qb, Kt, Vt);
    pam_attn<<<dim3(NBLKQ, S, BN), 256, 0, stream>>>(Qb, Kt, Vt, PACC, PSUM, m_range);
    pam_norm<<<dim3(NN / 64, BN), 256, 0, stream>>>(PACC, PSUM, out, S);
}

// Round 14
// 141.464 us; speedup vs baseline: 1.1136x; 1.1136x over previous
//
#include <hip/hip_runtime.h>

// PositionAttentionModule: B=2,C=64,C8=8,H=W=96,N=9216
// Round 14: R11 known-good structure (transposed QK via MFMA, P in regs,
// folded shift/log2e, raw v_exp_f32, loads-before-barrier, single v_s buffer,
// launch_bounds(256,4), S=12) with the one untested isolated lever:
// MCHUNK=128/PSTR=132 -> smaller live set (vbuf[4]/aK[4]), LDS 16.9 KB,
// 33% shorter barrier-to-barrier critical sections.
// Abandoned (HW-falsified): launch_bounds 5/6 (spill/abort), LDS dbuf
// (register spill, +39MB scratch), LDS-free swizzled-V (replay divergence).

#define BN 2
#define CC 64
#define C8K 8
#define NN 9216
#define MCHUNK 128
#define TQ 128                // query rows per block (4 waves x 32)
#define NBLKQ (NN / TQ)       // 72
#define PREP_PX 64
#define LOG2E 1.44269504f
#define PSTR 132              // shorts; 264B row: dword-pair stride 33 (odd mod 16)

typedef __attribute__((ext_vector_type(8))) short short8;
typedef __attribute__((ext_vector_type(16))) float f32x16;

// float offsets into workspace
#define OFF_QB 0                                   // bf16 [b][n][8], prescaled by log2e
#define OFF_KT (OFF_QB + BN * NN * C8K / 2)        // bf16 [b][m][8]
#define OFF_VT (OFF_KT + BN * NN * C8K / 2)        // bf16 [b][c][m]
#define OFF_PACC (OFF_VT + BN * NN * CC / 2)       // bf16 [sp][b][c][n]
// PSUM (fp32 [sp][b][n]) follows PACC

static __device__ inline unsigned f2bf(float x) {
    unsigned u = __builtin_bit_cast(unsigned, x);
    return (u + 0x7fff + ((u >> 16) & 1)) >> 16;   // RNE
}

#if __has_builtin(__builtin_amdgcn_cvt_pk_bf16_f32)
typedef __attribute__((ext_vector_type(2))) __bf16 bf16x2;
static __device__ inline unsigned pk_pair(float lo, float hi) {
    bf16x2 v = __builtin_amdgcn_cvt_pk_bf16_f32(lo, hi);   // lo -> D.lo, hi -> D.hi
    return __builtin_bit_cast(unsigned, v);
}
#else
static __device__ inline unsigned pk_pair(float lo, float hi) {
    unsigned ulo = __builtin_bit_cast(unsigned, lo) + 0x8000u;
    unsigned uhi = __builtin_bit_cast(unsigned, hi) + 0x8000u;
    return __builtin_amdgcn_perm(uhi, ulo, 0x07060302u);
}
#endif

__global__ __launch_bounds__(256) void pam_prep(
    const float* __restrict__ fm, const float* __restrict__ depth,
    const float* __restrict__ wa, const float* __restrict__ ba,
    const float* __restrict__ wb, const float* __restrict__ bb,
    const float* __restrict__ wc, const float* __restrict__ bc,
    const float* __restrict__ wd, const float* __restrict__ bd,
    unsigned short* __restrict__ Qb, unsigned short* __restrict__ Kt,
    unsigned short* __restrict__ Vt)
{
    __shared__ float s_wd[CC * CC];
    __shared__ float s_wb[C8K * CC], s_wc[C8K * CC];
    __shared__ float s_wa[CC], s_ba[CC], s_bd[CC];
    __shared__ float s_bb[C8K], s_bc[C8K];
    __shared__ float qp[4][PREP_PX][C8K + 1];

    int t = threadIdx.x;
    for (int i = t; i < CC * CC; i += 256) s_wd[i] = wd[i];
    for (int i = t; i < C8K * CC; i += 256) { s_wb[i] = wb[i]; s_wc[i] = wc[i]; }
    if (t < CC) { s_wa[t] = wa[t]; s_ba[t] = ba[t]; s_bd[t] = bd[t]; }
    if (t < C8K) { s_bb[t] = bb[t]; s_bc[t] = bc[t]; }
    __syncthreads();

    int px0 = blockIdx.x * PREP_PX;
    int b = px0 / NN;
    int m0 = px0 - b * NN;
    int px = t & 63, w = t >> 6;
    int m = m0 + px;
    int gidx = px0 + px;

    float d = depth[gidx];
    float df[CC];
#pragma unroll
    for (int i = 0; i < CC; ++i) df[i] = fmaxf(s_wa[i] * d + s_ba[i], 0.0f);

#pragma unroll 4
    for (int cc = 0; cc < 16; ++cc) {
        int c = w * 16 + cc;
        float acc = s_bd[c];
#pragma unroll
        for (int i = 0; i < CC; i += 4) {
            float4 wv = *(const float4*)&s_wd[c * CC + i];
            acc += wv.x * df[i] + wv.y * df[i + 1] + wv.z * df[i + 2] + wv.w * df[i + 3];
        }
        Vt[(b * CC + c) * NN + m] = (unsigned short)f2bf(acc);
    }

    {
        float k0 = s_bc[2 * w], k1 = s_bc[2 * w + 1];
#pragma unroll
        for (int i = 0; i < CC; ++i) {
            k0 += s_wc[(2 * w) * CC + i] * df[i];
            k1 += s_wc[(2 * w + 1) * CC + i] * df[i];
        }
        unsigned pkv = f2bf(k0) | (f2bf(k1) << 16);
        *(unsigned*)&Kt[(b * NN + m) * C8K + 2 * w] = pkv;
    }

    {
        float q[C8K];
#pragma unroll
        for (int k = 0; k < C8K; ++k) q[k] = (w == 0) ? s_bb[k] : 0.0f;
#pragma unroll
        for (int ii = 0; ii < 16; ++ii) {
            int i = w * 16 + ii;
            float f = fm[(b * CC + i) * NN + m];
#pragma unroll
            for (int k = 0; k < C8K; ++k) q[k] += s_wb[k * CC + i] * f;
        }
#pragma unroll
        for (int k = 0; k < C8K; ++k) qp[w][px][k] = q[k];
    }
    __syncthreads();
    {
        int px2 = t >> 2, k2 = (t & 3) * 2;
        float a0 = (qp[0][px2][k2] + qp[1][px2][k2] + qp[2][px2][k2] + qp[3][px2][k2]) * LOG2E;
        float a1 = (qp[0][px2][k2 + 1] + qp[1][px2][k2 + 1] + qp[2][px2][k2 + 1] + qp[3][px2][k2 + 1]) * LOG2E;
        unsigned pkv = f2bf(a0) | (f2bf(a1) << 16);
        *(unsigned*)&Qb[(px0 + px2) * C8K + k2] = pkv;
    }
}

// grid (72, S, B), block 256 = 4 waves; wave w -> qrows [w*32, w*32+32).
__global__ __launch_bounds__(256, 4) void pam_attn(
    const unsigned short* __restrict__ Qb, const unsigned short* __restrict__ Kt,
    const unsigned short* __restrict__ Vt,
    unsigned short* __restrict__ PACC, float* __restrict__ PSUM,
    int m_range)
{
    __shared__ unsigned short v_s[CC * PSTR];   // 16.9 KB bf16 [c][m]

    int t = threadIdx.x;
    int n0 = blockIdx.x * TQ;
    int split = blockIdx.y;
    int b = blockIdx.z;
    int m_start = split * m_range;
    int nchunk = m_range / MCHUNK;

    int lane = t & 63, w = t >> 6;
    int l31 = lane & 31, half = lane >> 5;

    // QK B-frag: Q[qrow=l31][k] for k<8 (half0); half1 k=8 slot carries the
    // folded shift constant -12*log2e; k=9..15 are zero.
    short8 bq = {};
    if (lane < 32) bq = *(const short8*)&Qb[(b * NN + n0 + w * 32 + l31) * C8K];
    else           bq[0] = (short)f2bf(-12.0f * LOG2E);

    // per-lane masks: force A-frag element 0 to 1.0 on half1 lanes (k=8 slot)
    const unsigned mand = half ? 0xFFFF0000u : 0xFFFFFFFFu;
    const unsigned mor  = half ? 0x00003F80u : 0u;

    f32x16 acc0 = {}, acc1 = {};
    float2 rs2 = {0.0f, 0.0f};

    // V A-frag base pointers (this lane's channel rows, permuted k-order)
    const unsigned short* vr0 = &v_s[l31 * PSTR + half * 4];
    const unsigned short* vr1 = &v_s[(32 + l31) * PSTR + half * 4];

    int vrow = t >> 2, vsl = t & 3;   // staging: channel row, 16B-segment lane

    for (int ch = 0; ch < nchunk; ++ch) {
        int m0 = m_start + ch * MCHUNK;
        // ---- issue global loads BEFORE barrier: no v_s dependency ----
        ulonglong2 vbuf[4];
        {
            const unsigned short* gsrc = &Vt[(b * CC + vrow) * NN + m0 + vsl * 8];
#pragma unroll
            for (int i = 0; i < 4; ++i)
                vbuf[i] = *(const ulonglong2*)(gsrc + i * 32);
        }
        // K-frags for 4 m-tiles: unconditional loads, then fix k=8 slot.
        union { unsigned u[4]; short8 s8; } aK[4];
#pragma unroll
        for (int mt = 0; mt < 4; ++mt)
            aK[mt].s8 = *(const short8*)&Kt[(b * NN + m0 + mt * 32 + l31) * C8K];
#pragma unroll
        for (int mt = 0; mt < 4; ++mt)
            aK[mt].u[0] = (aK[mt].u[0] & mand) | mor;

        __syncthreads();   // prior chunk's v_s reads complete
        // ---- LDS writes (8B pieces: 264B rows are 8B-aligned) ----
        {
            unsigned long long* ldst =
                (unsigned long long*)&v_s[vrow * PSTR + vsl * 8];
#pragma unroll
            for (int i = 0; i < 4; ++i) {
                ldst[i * 8 + 0] = vbuf[i].x;
                ldst[i * 8 + 1] = vbuf[i].y;
            }
        }
        __syncthreads();

#pragma unroll
        for (int mt = 0; mt < 4; ++mt) {
            // ---- QK^T transposed: D[m][qrow], already shifted & log2-scaled ----
            f32x16 s = __builtin_amdgcn_mfma_f32_32x32x16_bf16(aK[mt].s8, bq, (f32x16){}, 0, 0, 0);
            // ---- raw v_exp_f32 + rowsum + pack ----
            unsigned qd[8];
#pragma unroll
            for (int i = 0; i < 8; ++i) {
                float e0 = __builtin_amdgcn_exp2f(s[2 * i]);
                float e1 = __builtin_amdgcn_exp2f(s[2 * i + 1]);
                rs2.x += e0; rs2.y += e1;
                qd[i] = pk_pair(e0, e1);
            }
            // ---- PV: B = qd verbatim; A = v_s with permuted k-order ----
#pragma unroll
            for (int ks = 0; ks < 2; ++ks) {
                union { unsigned u[4]; short8 s8; } Bp;
#pragma unroll
                for (int i = 0; i < 4; ++i) Bp.u[i] = qd[ks * 4 + i];
                const int off = mt * 32 + ks * 16;
                union { unsigned long long d[2]; short8 s8; } A0, A1;
                A0.d[0] = *(const unsigned long long*)(vr0 + off);
                A0.d[1] = *(const unsigned long long*)(vr0 + off + 8);
                A1.d[0] = *(const unsigned long long*)(vr1 + off);
                A1.d[1] = *(const unsigned long long*)(vr1 + off + 8);
                acc0 = __builtin_amdgcn_mfma_f32_32x32x16_bf16(A0.s8, Bp.s8, acc0, 0, 0, 0);
                acc1 = __builtin_amdgcn_mfma_f32_32x32x16_bf16(A1.s8, Bp.s8, acc1, 0, 0, 0);
            }
        }
    }

    // ---- epilogue ----
    float rsum = rs2.x + rs2.y;
    rsum += __shfl_xor(rsum, 32);
    if (lane < 32)
        PSUM[(split * BN + b) * NN + n0 + w * 32 + l31] = rsum;

    // D[c][qrow]: lane l31 = qrow (n), reg -> c = 8*(reg>>2)+(reg&3)+4*half
    {
        int slabc = (split * BN + b) * CC;
        int nidx = n0 + w * 32 + l31;
#pragma unroll
        for (int reg = 0; reg < 16; ++reg) {
            int c = 8 * (reg >> 2) + (reg & 3) + 4 * half;
            PACC[(slabc + c) * NN + nidx] = (unsigned short)f2bf(acc0[reg]);
            PACC[(slabc + 32 + c) * NN + nidx] = (unsigned short)f2bf(acc1[reg]);
        }
    }
}

// out[b][c][n] = sum_sp PACC[sp][b][c][n] / sum_sp PSUM[sp][b][n]
__global__ __launch_bounds__(256) void pam_norm(
    const unsigned short* __restrict__ PACC, const float* __restrict__ PSUM,
    float* __restrict__ out, int S)
{
    __shared__ float s_inv[64];
    int t = threadIdx.x;
    int n0 = blockIdx.x * 64;
    int b = blockIdx.y;
    if (t < 64) {
        float s = 0.0f;
        for (int sp = 0; sp < S; ++sp) s += PSUM[(sp * BN + b) * NN + n0 + t];
        s_inv[t] = 1.0f / s;
    }
    __syncthreads();

    int c = t >> 2, ng = t & 3;       // channel, 16-n group
    int nb = n0 + ng * 16;
    float a[16];
#pragma unroll
    for (int j = 0; j < 16; ++j) a[j] = 0.0f;

    for (int sp = 0; sp < S; ++sp) {
        const unsigned short* p = &PACC[((sp * BN + b) * CC + c) * NN + nb];
        uint4 u0 = *(const uint4*)p;
        uint4 u1 = *(const uint4*)(p + 8);
        const unsigned uu[8] = {u0.x, u0.y, u0.z, u0.w, u1.x, u1.y, u1.z, u1.w};
#pragma unroll
        for (int i = 0; i < 8; ++i) {
            a[2 * i]     += __builtin_bit_cast(float, uu[i] << 16);
            a[2 * i + 1] += __builtin_bit_cast(float, uu[i] & 0xffff0000u);
        }
    }
    float* o = &out[(b * CC + c) * NN + nb];
#pragma unroll
    for (int j4 = 0; j4 < 4; ++j4) {
        float4 v;
        v.x = a[j4 * 4 + 0] * s_inv[ng * 16 + j4 * 4 + 0];
        v.y = a[j4 * 4 + 1] * s_inv[ng * 16 + j4 * 4 + 1];
        v.z = a[j4 * 4 + 2] * s_inv[ng * 16 + j4 * 4 + 2];
        v.w = a[j4 * 4 + 3] * s_inv[ng * 16 + j4 * 4 + 3];
        *(float4*)(o + j4 * 4) = v;
    }
}

extern "C" void kernel_launch(void* const* d_in, const int* in_sizes, int n_in,
                              void* d_out, int out_size, void* d_ws, size_t ws_size,
                              hipStream_t stream) {
    const float* fm    = (const float*)d_in[0];
    const float* depth = (const float*)d_in[1];
    const float* wa    = (const float*)d_in[2];
    const float* ba    = (const float*)d_in[3];
    const float* wb    = (const float*)d_in[4];
    const float* bb    = (const float*)d_in[5];
    const float* wc    = (const float*)d_in[6];
    const float* bc    = (const float*)d_in[7];
    const float* wd    = (const float*)d_in[8];
    const float* bd    = (const float*)d_in[9];
    float* out = (float*)d_out;

    float* ws = (float*)d_ws;
    unsigned short* Qb = (unsigned short*)(ws + OFF_QB);
    unsigned short* Kt = (unsigned short*)(ws + OFF_KT);
    unsigned short* Vt = (unsigned short*)(ws + OFF_VT);
    unsigned short* PACC = (unsigned short*)(ws + OFF_PACC);

    // pick largest split whose PACC(bf16)+PSUM fit: 12 -> 8 -> 4
    int S = 12;
    while (S > 4) {
        size_t need = (size_t)OFF_PACC * 4
                    + (size_t)S * BN * NN * CC * 2      // PACC bf16
                    + (size_t)S * BN * NN * 4;          // PSUM fp32
        if (need <= ws_size) break;
        S -= 4;
    }
    float* PSUM = (float*)(PACC + (size_t)S * BN * NN * CC);
    int m_range = NN / S;   // 12->768, 8->1152, 4->2304; all % 128 == 0

    pam_prep<<<dim3((BN * NN) / PREP_PX), 256, 0, stream>>>(
        fm, depth, wa, ba, wb, bb, wc, bc, wd, bd, Qb, Kt, Vt);
    pam_attn<<<dim3(NBLKQ, S, BN), 256, 0, stream>>>(Qb, Kt, Vt, PACC, PSUM, m_range);
    pam_norm<<<dim3(NN / 64, BN), 256, 0, stream>>>(PACC, PSUM, out, S);
}